// Round 1
// baseline (506.016 us; speedup 1.0000x reference)
//
#include <hip/hip_runtime.h>
#include <math.h>

#define Bn 8
#define Hn 16
#define Sn 4096
#define Dn 64
#define BHn 128
#define CW 3.834951969714103e-4f   // pi/2/4096

typedef __attribute__((ext_vector_type(8))) short short8;
typedef __attribute__((ext_vector_type(4))) float f32x4;

__device__ __forceinline__ unsigned short f2bf(float x) {
    unsigned int u = __float_as_uint(x);
    u += 0x7fffu + ((u >> 16) & 1u);   // round-to-nearest-even
    return (unsigned short)(u >> 16);
}
__device__ __forceinline__ unsigned int pack2(float lo, float hi) {
    return (unsigned int)f2bf(lo) | ((unsigned int)f2bf(hi) << 16);
}
__device__ __forceinline__ float nneg(float x) {
    return x < 0.f ? __expf(x) : x + 1.f;
}

// ---------------------------------------------------------------------------
// init: zero KV accumulator (4 MiB) + detect mask storage layout.
// flag=1 -> int32 storage, flag=0 -> byte (bool) storage.
// ---------------------------------------------------------------------------
__global__ __launch_bounds__(256) void k_init(float4* kv4, int* flag,
                                              const unsigned char* mask_raw) {
    int i = blockIdx.x * 256 + threadIdx.x;
    kv4[i] = make_float4(0.f, 0.f, 0.f, 0.f);   // grid sized exactly
    if (blockIdx.x == 0) {
        __shared__ int s_any;
        if (threadIdx.x == 0) s_any = 0;
        __syncthreads();
        int any = 0;
        int base = threadIdx.x * 16;
        #pragma unroll
        for (int j = 0; j < 16; j++) {
            int idx = base + j;
            if ((idx & 3) && mask_raw[idx]) any = 1;
        }
        if (any) s_any = 1;
        __syncthreads();
        if (threadIdx.x == 0) *flag = s_any ? 0 : 1;
    }
}

// ---------------------------------------------------------------------------
// phase 1: KV_c[e][d] = sum_s kf(k[s,d])*cos(s) * v[s,e]   (and sin variant)
// stored TRANSPOSED [e][d] in ws, fp32, accumulated with atomics over 8 splits.
// grid = 128 bh * 8 splits, block = 256 (4 waves; wave w owns e-tile w).
// LDS: bf16 transposed tiles [64][72] (stride 72 shorts = 144 B, 16B aligned).
// ---------------------------------------------------------------------------
__global__ __launch_bounds__(256) void k_phase1(const float* __restrict__ kk,
                                                const float* __restrict__ vv,
                                                float* __restrict__ kv) {
    __shared__ unsigned int ldsKc[64 * 36];
    __shared__ unsigned int ldsKs[64 * 36];
    __shared__ unsigned int ldsV [64 * 36];
    const int t    = threadIdx.x;
    const int bh   = blockIdx.x >> 3;
    const int sblk = (blockIdx.x & 7) << 9;    // *512
    const int c    = t & 15;                   // column group (x4)
    const int rp   = t >> 4;                   // row-pair 0..15
    const int lane = t & 63;
    const int w    = t >> 6;                   // wave id == e-tile
    const int n    = lane & 15;
    const int q4   = lane >> 4;                // quad
    const float* kb = kk + (size_t)bh * (Sn * Dn);
    const float* vb = vv + (size_t)bh * (Sn * Dn);
    const unsigned short* ldsKc_h = (const unsigned short*)ldsKc;
    const unsigned short* ldsKs_h = (const unsigned short*)ldsKs;
    const unsigned short* ldsV_h  = (const unsigned short*)ldsV;

    f32x4 accC[4], accS[4];
    #pragma unroll
    for (int i = 0; i < 4; i++) {
        accC[i] = (f32x4){0.f, 0.f, 0.f, 0.f};
        accS[i] = (f32x4){0.f, 0.f, 0.f, 0.f};
    }

    for (int chunk = 0; chunk < 8; chunk++) {
        const int s0 = sblk + chunk * 64;
        // ---- stage 64 rows of kc/ks/v, transposed, bf16, s-pairs packed ----
        #pragma unroll
        for (int half = 0; half < 2; half++) {
            int r0  = half * 32 + rp * 2;
            int s_a = s0 + r0, s_b = s0 + r0 + 1;
            float4 ka  = *(const float4*)(kb + (size_t)s_a * Dn + c * 4);
            float4 kb4 = *(const float4*)(kb + (size_t)s_b * Dn + c * 4);
            float4 va  = *(const float4*)(vb + (size_t)s_a * Dn + c * 4);
            float4 vb4 = *(const float4*)(vb + (size_t)s_b * Dn + c * 4);
            float csa, sna, csb, snb;
            __sincosf(CW * (float)s_a, &sna, &csa);
            __sincosf(CW * (float)s_b, &snb, &csb);
            float fa[4] = {nneg(ka.x),  nneg(ka.y),  nneg(ka.z),  nneg(ka.w)};
            float fb[4] = {nneg(kb4.x), nneg(kb4.y), nneg(kb4.z), nneg(kb4.w)};
            float ga[4] = {va.x, va.y, va.z, va.w};
            float gb[4] = {vb4.x, vb4.y, vb4.z, vb4.w};
            int sp = half * 16 + rp;
            #pragma unroll
            for (int j = 0; j < 4; j++) {
                int d = c * 4 + j;
                ldsKc[d * 36 + sp] = pack2(fa[j] * csa, fb[j] * csb);
                ldsKs[d * 36 + sp] = pack2(fa[j] * sna, fb[j] * snb);
                ldsV [d * 36 + sp] = pack2(ga[j],        gb[j]);
            }
        }
        __syncthreads();
        // ---- MFMA: A = KC^T / KS^T (m=d, k=s), B = V (k=s, n=e) ----
        #pragma unroll
        for (int ks = 0; ks < 2; ks++) {
            short8 Bv = *(const short8*)(ldsV_h + (w * 16 + n) * 72 + ks * 32 + q4 * 8);
            #pragma unroll
            for (int dt = 0; dt < 4; dt++) {
                short8 Ac = *(const short8*)(ldsKc_h + (dt * 16 + n) * 72 + ks * 32 + q4 * 8);
                short8 As = *(const short8*)(ldsKs_h + (dt * 16 + n) * 72 + ks * 32 + q4 * 8);
                accC[dt] = __builtin_amdgcn_mfma_f32_16x16x32_bf16(Ac, Bv, accC[dt], 0, 0, 0);
                accS[dt] = __builtin_amdgcn_mfma_f32_16x16x32_bf16(As, Bv, accS[dt], 0, 0, 0);
            }
        }
        __syncthreads();
    }
    // ---- accumulate into ws: KV transposed [bh][{c,s}][e][d] ----
    float* base = kv + (size_t)bh * 2 * 4096;
    int e = w * 16 + n;
    #pragma unroll
    for (int dt = 0; dt < 4; dt++) {
        #pragma unroll
        for (int r = 0; r < 4; r++) {
            int d = dt * 16 + q4 * 4 + r;   // C layout: row = quad*4 + reg
            atomicAdd(base +        e * 64 + d, accC[dt][r]);
            atomicAdd(base + 4096 + e * 64 + d, accS[dt][r]);
        }
    }
}

// ---------------------------------------------------------------------------
// phase 2: out[s,e] = (qc[s,:]·KV_c[:,e] + qs[s,:]·KV_s[:,e]) * 0.125
// qc = nneg(q)*cos(s)*mask, qs = nneg(q)*sin(s)*mask (row constants per lane).
// grid = 128 bh * 8 chunks(512 s), block = 256. B-frags hoisted to VGPRs.
// ---------------------------------------------------------------------------
__global__ __launch_bounds__(256) void k_phase2(const float* __restrict__ qq,
                                                const void* __restrict__ mask_raw,
                                                const float* __restrict__ kv,
                                                const int* __restrict__ flag,
                                                float* __restrict__ out) {
    __shared__ unsigned int ldsC[64 * 36];
    __shared__ unsigned int ldsS[64 * 36];
    const int t    = threadIdx.x;
    const int bh   = blockIdx.x >> 3;
    const int sblk = (blockIdx.x & 7) << 9;
    const int b    = bh >> 4;                  // H = 16
    const int lane = t & 63;
    const int w    = t >> 6;
    const int n    = lane & 15;
    const int q4   = lane >> 4;
    const int iflag = *flag;

    // ---- stage KV (already transposed [e][d]) -> LDS bf16 ----
    const float* kvb = kv + (size_t)bh * 2 * 4096;
    for (int i = t; i < 2048; i += 256) {
        int e = i >> 5, dp = i & 31;
        float2 xc = *(const float2*)(kvb +        e * 64 + dp * 2);
        float2 xs = *(const float2*)(kvb + 4096 + e * 64 + dp * 2);
        ldsC[e * 36 + dp] = pack2(xc.x, xc.y);
        ldsS[e * 36 + dp] = pack2(xs.x, xs.y);
    }
    __syncthreads();
    const unsigned short* ldsC_h = (const unsigned short*)ldsC;
    const unsigned short* ldsS_h = (const unsigned short*)ldsS;
    short8 Bc[4][2], Bs[4][2];
    #pragma unroll
    for (int et = 0; et < 4; et++) {
        #pragma unroll
        for (int ks = 0; ks < 2; ks++) {
            Bc[et][ks] = *(const short8*)(ldsC_h + (et * 16 + n) * 72 + ks * 32 + q4 * 8);
            Bs[et][ks] = *(const short8*)(ldsS_h + (et * 16 + n) * 72 + ks * 32 + q4 * 8);
        }
    }

    const float* qb = qq + (size_t)bh * (Sn * Dn);
    float* ob       = out + (size_t)bh * (Sn * Dn);
    const unsigned char* m8 = (const unsigned char*)mask_raw;
    const int* m32          = (const int*)mask_raw;

    for (int strip = 0; strip < 8; strip++) {
        int s_base = sblk + (strip * 4 + w) * 16;
        int s_row  = s_base + n;               // A-layout: m = lane&15
        float mval;
        if (iflag) mval = m32[b * Sn + s_row] ? 1.f : 0.f;
        else       mval = m8 [b * Sn + s_row] ? 1.f : 0.f;
        float cs, sn;
        __sincosf(CW * (float)s_row, &sn, &cs);
        cs *= mval; sn *= mval;
        const float* qp = qb + (size_t)s_row * 64 + q4 * 8;
        float4 q0 = *(const float4*)(qp);
        float4 q1 = *(const float4*)(qp + 4);
        float4 q2 = *(const float4*)(qp + 32);
        float4 q3 = *(const float4*)(qp + 36);
        float f[16];
        f[0]=nneg(q0.x); f[1]=nneg(q0.y); f[2]=nneg(q0.z); f[3]=nneg(q0.w);
        f[4]=nneg(q1.x); f[5]=nneg(q1.y); f[6]=nneg(q1.z); f[7]=nneg(q1.w);
        f[8]=nneg(q2.x); f[9]=nneg(q2.y); f[10]=nneg(q2.z); f[11]=nneg(q2.w);
        f[12]=nneg(q3.x); f[13]=nneg(q3.y); f[14]=nneg(q3.z); f[15]=nneg(q3.w);
        short8 Ac0, As0, Ac1, As1;
        #pragma unroll
        for (int j = 0; j < 8; j++) {
            Ac0[j] = (short)f2bf(f[j] * cs);
            As0[j] = (short)f2bf(f[j] * sn);
            Ac1[j] = (short)f2bf(f[8 + j] * cs);
            As1[j] = (short)f2bf(f[8 + j] * sn);
        }
        f32x4 acc[4];
        #pragma unroll
        for (int et = 0; et < 4; et++) acc[et] = (f32x4){0.f, 0.f, 0.f, 0.f};
        #pragma unroll
        for (int et = 0; et < 4; et++) {
            acc[et] = __builtin_amdgcn_mfma_f32_16x16x32_bf16(Ac0, Bc[et][0], acc[et], 0, 0, 0);
            acc[et] = __builtin_amdgcn_mfma_f32_16x16x32_bf16(Ac1, Bc[et][1], acc[et], 0, 0, 0);
            acc[et] = __builtin_amdgcn_mfma_f32_16x16x32_bf16(As0, Bs[et][0], acc[et], 0, 0, 0);
            acc[et] = __builtin_amdgcn_mfma_f32_16x16x32_bf16(As1, Bs[et][1], acc[et], 0, 0, 0);
        }
        // C layout: col = lane&15, row = quad*4 + reg
        #pragma unroll
        for (int et = 0; et < 4; et++) {
            #pragma unroll
            for (int r = 0; r < 4; r++) {
                int row = q4 * 4 + r;
                ob[(size_t)(s_base + row) * 64 + et * 16 + n] = acc[et][r] * 0.125f;
            }
        }
    }
}

extern "C" void kernel_launch(void* const* d_in, const int* in_sizes, int n_in,
                              void* d_out, int out_size, void* d_ws, size_t ws_size,
                              hipStream_t stream) {
    const float* q = (const float*)d_in[0];
    const float* k = (const float*)d_in[1];
    const float* v = (const float*)d_in[2];
    const void* mask = d_in[3];
    int*   flag = (int*)d_ws;
    float* kv   = (float*)((char*)d_ws + 256);   // 4 MiB KV accumulator

    k_init  <<<1024, 256, 0, stream>>>((float4*)kv, flag, (const unsigned char*)mask);
    k_phase1<<<1024, 256, 0, stream>>>(k, v, kv);
    k_phase2<<<1024, 256, 0, stream>>>(q, mask, kv, flag, (float*)d_out);
}

// Round 2
// 424.432 us; speedup vs baseline: 1.1922x; 1.1922x over previous
//
#include <hip/hip_runtime.h>
#include <math.h>

#define Sn 4096
#define Dn 64
#define CW 3.834951969714103e-4f   // pi/2/4096
#define P1S 34                     // LDS row stride in uints (8B-aligned, conflict-free)

typedef __attribute__((ext_vector_type(8))) short short8;
typedef __attribute__((ext_vector_type(4))) float f32x4;

__device__ __forceinline__ unsigned short f2bf(float x) {
    unsigned int u = __float_as_uint(x);
    u += 0x7fffu + ((u >> 16) & 1u);   // round-to-nearest-even
    return (unsigned short)(u >> 16);
}
__device__ __forceinline__ unsigned int pack2(float lo, float hi) {
    return (unsigned int)f2bf(lo) | ((unsigned int)f2bf(hi) << 16);
}
__device__ __forceinline__ float nneg(float x) {
    return x < 0.f ? __expf(x) : x + 1.f;
}
__device__ __forceinline__ short8 ld_frag(const unsigned int* p) {
    uint2 a = *(const uint2*)p;
    uint2 b = *(const uint2*)(p + 2);
    union { unsigned int u[4]; short8 s; } r;
    r.u[0] = a.x; r.u[1] = a.y; r.u[2] = b.x; r.u[3] = b.y;
    return r.s;
}

// ---------------------------------------------------------------------------
// init: zero 4 MiB KV accumulator + detect token_mask storage (int32 vs byte)
// ---------------------------------------------------------------------------
__global__ __launch_bounds__(256) void k_init(float4* kv4, int* flag,
                                              const unsigned char* mask_raw) {
    int i = blockIdx.x * 256 + threadIdx.x;
    kv4[i] = make_float4(0.f, 0.f, 0.f, 0.f);   // grid sized exactly
    if (blockIdx.x == 0) {
        __shared__ int s_any;
        if (threadIdx.x == 0) s_any = 0;
        __syncthreads();
        int any = 0;
        int base = threadIdx.x * 16;
        #pragma unroll
        for (int j = 0; j < 16; j++) {
            int idx = base + j;
            if ((idx & 3) && mask_raw[idx]) any = 1;
        }
        if (any) s_any = 1;
        __syncthreads();
        if (threadIdx.x == 0) *flag = s_any ? 0 : 1;
    }
}

// ---------------------------------------------------------------------------
// phase 1: KV[d][e] = sum_s kf(k[s,d])*cos(s)*v[s,e]  (and sin variant)
// grid = 128 bh * 16 splits (256 s each), block=256. Software-pipelined:
// prefetch next 64-row chunk into regs during current chunk's MFMA.
// LDS: bf16 transposed [64 rows][34 uints] (rows = d for Kc/Ks, = e for V).
// KV stored [d][e] fp32 in ws -> lane-contiguous atomics (line-coalesced).
// ---------------------------------------------------------------------------
__global__ __launch_bounds__(256) void k_phase1(const float* __restrict__ kk,
                                                const float* __restrict__ vv,
                                                float* __restrict__ kv) {
    __shared__ unsigned int ldsKc[64 * P1S];
    __shared__ unsigned int ldsKs[64 * P1S];
    __shared__ unsigned int ldsV [64 * P1S];
    const int t    = threadIdx.x;
    const int bh   = blockIdx.x >> 4;
    const int sblk = (blockIdx.x & 15) << 8;   // *256
    const int c    = t & 15;                   // d-group (4 d's)
    const int rp   = t >> 4;                   // s-quad 0..15
    const int lane = t & 63;
    const int w    = t >> 6;                   // wave id == e-tile
    const int n    = lane & 15;
    const int q4   = lane >> 4;
    const float* kb = kk + (size_t)bh * (Sn * Dn);
    const float* vb = vv + (size_t)bh * (Sn * Dn);

    f32x4 accC[4], accS[4];
    #pragma unroll
    for (int i = 0; i < 4; i++) {
        accC[i] = (f32x4){0.f, 0.f, 0.f, 0.f};
        accS[i] = (f32x4){0.f, 0.f, 0.f, 0.f};
    }

    float4 pk[2][4], pv[2][4];
    {   // preload chunk 0
        const float* kp = kb + (size_t)(sblk + rp * 4) * Dn + c * 4;
        const float* vp = vb + (size_t)(sblk + rp * 4) * Dn + c * 4;
        #pragma unroll
        for (int i = 0; i < 4; i++) {
            pk[0][i] = *(const float4*)(kp + i * Dn);
            pv[0][i] = *(const float4*)(vp + i * Dn);
        }
    }

    #pragma unroll
    for (int chunk = 0; chunk < 4; chunk++) {
        const int cur = chunk & 1, nxt = cur ^ 1;
        const int s0 = sblk + chunk * 64;
        // ---- transform current chunk + stage to LDS (b64 writes) ----
        float cs[4], sn[4], fk[4][4], fv[4][4];
        #pragma unroll
        for (int i = 0; i < 4; i++) {
            __sincosf(CW * (float)(s0 + rp * 4 + i), &sn[i], &cs[i]);
            fk[i][0] = nneg(pk[cur][i].x); fk[i][1] = nneg(pk[cur][i].y);
            fk[i][2] = nneg(pk[cur][i].z); fk[i][3] = nneg(pk[cur][i].w);
            fv[i][0] = pv[cur][i].x; fv[i][1] = pv[cur][i].y;
            fv[i][2] = pv[cur][i].z; fv[i][3] = pv[cur][i].w;
        }
        #pragma unroll
        for (int j = 0; j < 4; j++) {
            int d = c * 4 + j;
            uint2 wc, wsn, wv;
            wc.x  = pack2(fk[0][j] * cs[0], fk[1][j] * cs[1]);
            wc.y  = pack2(fk[2][j] * cs[2], fk[3][j] * cs[3]);
            wsn.x = pack2(fk[0][j] * sn[0], fk[1][j] * sn[1]);
            wsn.y = pack2(fk[2][j] * sn[2], fk[3][j] * sn[3]);
            wv.x  = pack2(fv[0][j], fv[1][j]);
            wv.y  = pack2(fv[2][j], fv[3][j]);
            *(uint2*)&ldsKc[d * P1S + rp * 2] = wc;
            *(uint2*)&ldsKs[d * P1S + rp * 2] = wsn;
            *(uint2*)&ldsV [d * P1S + rp * 2] = wv;
        }
        __syncthreads();
        // ---- prefetch next chunk (latency hidden behind MFMA section) ----
        if (chunk < 3) {
            const float* kp = kb + (size_t)(s0 + 64 + rp * 4) * Dn + c * 4;
            const float* vp = vb + (size_t)(s0 + 64 + rp * 4) * Dn + c * 4;
            #pragma unroll
            for (int i = 0; i < 4; i++) {
                pk[nxt][i] = *(const float4*)(kp + i * Dn);
                pv[nxt][i] = *(const float4*)(vp + i * Dn);
            }
        }
        // ---- MFMA: A = Kc^T/Ks^T (m=d,k=s), B = V (k=s,n=e) ----
        #pragma unroll
        for (int ks = 0; ks < 2; ks++) {
            short8 Bv = ld_frag(&ldsV[(w * 16 + n) * P1S + ks * 16 + q4 * 4]);
            #pragma unroll
            for (int dt = 0; dt < 4; dt++) {
                short8 Ac = ld_frag(&ldsKc[(dt * 16 + n) * P1S + ks * 16 + q4 * 4]);
                short8 As = ld_frag(&ldsKs[(dt * 16 + n) * P1S + ks * 16 + q4 * 4]);
                accC[dt] = __builtin_amdgcn_mfma_f32_16x16x32_bf16(Ac, Bv, accC[dt], 0, 0, 0);
                accS[dt] = __builtin_amdgcn_mfma_f32_16x16x32_bf16(As, Bv, accS[dt], 0, 0, 0);
            }
        }
        __syncthreads();
    }
    // ---- atomics into KV[d][e]: lanes n contiguous -> 4 lines / instr ----
    float* base = kv + (size_t)bh * 2 * 4096;
    const int e = w * 16 + n;
    #pragma unroll
    for (int dt = 0; dt < 4; dt++) {
        #pragma unroll
        for (int r = 0; r < 4; r++) {
            int d = dt * 16 + q4 * 4 + r;   // C layout: row = quad*4 + reg
            atomicAdd(base +        d * 64 + e, accC[dt][r]);
            atomicAdd(base + 4096 + d * 64 + e, accS[dt][r]);
        }
    }
}

// ---------------------------------------------------------------------------
// phase 2: out[s,e] = (qc[s,:]·KV_c[:,e] + qs[s,:]·KV_s[:,e]) * 0.125
// grid = 128 bh * 16 chunks (256 s each), block=256, 4 strips of 64 s.
// B-frags gathered straight from global KV[d][e] (L2-hot), no LDS/barrier.
// q for strip+1 prefetched before strip's MFMAs.
// ---------------------------------------------------------------------------
__global__ __launch_bounds__(256) void k_phase2(const float* __restrict__ qq,
                                                const void* __restrict__ mask_raw,
                                                const float* __restrict__ kv,
                                                const int* __restrict__ flag,
                                                float* __restrict__ out) {
    const int t    = threadIdx.x;
    const int bh   = blockIdx.x >> 4;
    const int sblk = (blockIdx.x & 15) << 8;
    const int b    = bh >> 4;                  // H = 16
    const int lane = t & 63;
    const int w    = t >> 6;
    const int n    = lane & 15;
    const int q4   = lane >> 4;
    const int iflag = *flag;

    // ---- gather B-frags from KV[d][e] (fp32 -> bf16) ----
    const float* kvb = kv + (size_t)bh * 8192;
    short8 Bc[4][2], Bs[4][2];
    #pragma unroll
    for (int et = 0; et < 4; et++) {
        const int e = et * 16 + n;
        #pragma unroll
        for (int ks = 0; ks < 2; ks++) {
            const int d0 = ks * 32 + q4 * 8;
            union { unsigned int u[4]; short8 s; } uc, us;
            #pragma unroll
            for (int jj = 0; jj < 4; jj++) {
                float c0 = kvb[(size_t)(d0 + 2 * jj)     * 64 + e];
                float c1 = kvb[(size_t)(d0 + 2 * jj + 1) * 64 + e];
                float s0 = kvb[4096 + (size_t)(d0 + 2 * jj)     * 64 + e];
                float s1 = kvb[4096 + (size_t)(d0 + 2 * jj + 1) * 64 + e];
                uc.u[jj] = pack2(c0, c1);
                us.u[jj] = pack2(s0, s1);
            }
            Bc[et][ks] = uc.s;
            Bs[et][ks] = us.s;
        }
    }

    const float* qb = qq + (size_t)bh * (Sn * Dn);
    float* ob       = out + (size_t)bh * (Sn * Dn);
    const unsigned char* m8 = (const unsigned char*)mask_raw;
    const int* m32          = (const int*)mask_raw;

    float4 pq[2][4];
    float  pmv[2];
    {   // preload strip 0
        int s_row = sblk + w * 16 + n;
        const float* qp = qb + (size_t)s_row * Dn + q4 * 8;
        pq[0][0] = *(const float4*)(qp);
        pq[0][1] = *(const float4*)(qp + 4);
        pq[0][2] = *(const float4*)(qp + 32);
        pq[0][3] = *(const float4*)(qp + 36);
        pmv[0] = iflag ? (m32[b * Sn + s_row] ? 1.f : 0.f)
                       : (m8 [b * Sn + s_row] ? 1.f : 0.f);
    }

    #pragma unroll
    for (int strip = 0; strip < 4; strip++) {
        const int cur = strip & 1, nxt = cur ^ 1;
        const int s_base = sblk + strip * 64 + w * 16;
        const int s_row  = s_base + n;         // A-layout: m = lane&15
        float cs, snv;
        __sincosf(CW * (float)s_row, &snv, &cs);
        cs *= pmv[cur]; snv *= pmv[cur];
        float f[16];
        f[0]  = nneg(pq[cur][0].x); f[1]  = nneg(pq[cur][0].y);
        f[2]  = nneg(pq[cur][0].z); f[3]  = nneg(pq[cur][0].w);
        f[4]  = nneg(pq[cur][1].x); f[5]  = nneg(pq[cur][1].y);
        f[6]  = nneg(pq[cur][1].z); f[7]  = nneg(pq[cur][1].w);
        f[8]  = nneg(pq[cur][2].x); f[9]  = nneg(pq[cur][2].y);
        f[10] = nneg(pq[cur][2].z); f[11] = nneg(pq[cur][2].w);
        f[12] = nneg(pq[cur][3].x); f[13] = nneg(pq[cur][3].y);
        f[14] = nneg(pq[cur][3].z); f[15] = nneg(pq[cur][3].w);
        short8 Ac0, As0, Ac1, As1;
        #pragma unroll
        for (int j = 0; j < 8; j++) {
            Ac0[j] = (short)f2bf(f[j] * cs);
            As0[j] = (short)f2bf(f[j] * snv);
            Ac1[j] = (short)f2bf(f[8 + j] * cs);
            As1[j] = (short)f2bf(f[8 + j] * snv);
        }
        // ---- prefetch next strip's q + mask ----
        if (strip < 3) {
            int s_row2 = sblk + (strip + 1) * 64 + w * 16 + n;
            const float* qp = qb + (size_t)s_row2 * Dn + q4 * 8;
            pq[nxt][0] = *(const float4*)(qp);
            pq[nxt][1] = *(const float4*)(qp + 4);
            pq[nxt][2] = *(const float4*)(qp + 32);
            pq[nxt][3] = *(const float4*)(qp + 36);
            pmv[nxt] = iflag ? (m32[b * Sn + s_row2] ? 1.f : 0.f)
                             : (m8 [b * Sn + s_row2] ? 1.f : 0.f);
        }
        f32x4 acc[4];
        #pragma unroll
        for (int et = 0; et < 4; et++) acc[et] = (f32x4){0.f, 0.f, 0.f, 0.f};
        #pragma unroll
        for (int et = 0; et < 4; et++) {
            acc[et] = __builtin_amdgcn_mfma_f32_16x16x32_bf16(Ac0, Bc[et][0], acc[et], 0, 0, 0);
            acc[et] = __builtin_amdgcn_mfma_f32_16x16x32_bf16(Ac1, Bc[et][1], acc[et], 0, 0, 0);
            acc[et] = __builtin_amdgcn_mfma_f32_16x16x32_bf16(As0, Bs[et][0], acc[et], 0, 0, 0);
            acc[et] = __builtin_amdgcn_mfma_f32_16x16x32_bf16(As1, Bs[et][1], acc[et], 0, 0, 0);
        }
        // C layout: col = lane&15 (=e), row = quad*4 + reg (=s offset)
        #pragma unroll
        for (int et = 0; et < 4; et++) {
            #pragma unroll
            for (int r = 0; r < 4; r++) {
                int row = q4 * 4 + r;
                ob[(size_t)(s_base + row) * 64 + et * 16 + n] = acc[et][r] * 0.125f;
            }
        }
    }
}

extern "C" void kernel_launch(void* const* d_in, const int* in_sizes, int n_in,
                              void* d_out, int out_size, void* d_ws, size_t ws_size,
                              hipStream_t stream) {
    const float* q = (const float*)d_in[0];
    const float* k = (const float*)d_in[1];
    const float* v = (const float*)d_in[2];
    const void* mask = d_in[3];
    int*   flag = (int*)d_ws;
    float* kv   = (float*)((char*)d_ws + 256);   // 4 MiB KV accumulator

    k_init  <<<1024, 256, 0, stream>>>((float4*)kv, flag, (const unsigned char*)mask);
    k_phase1<<<2048, 256, 0, stream>>>(k, v, kv);
    k_phase2<<<2048, 256, 0, stream>>>(q, mask, kv, flag, (float*)d_out);
}

// Round 3
// 419.511 us; speedup vs baseline: 1.2062x; 1.0117x over previous
//
#include <hip/hip_runtime.h>
#include <math.h>

#define Sn 4096
#define Dn 64
#define CW 3.834951969714103e-4f   // pi/2/4096
#define P1S 34                     // LDS row stride in uints
#define LDSU (64 * P1S)            // uints per staged matrix

typedef __attribute__((ext_vector_type(8))) short short8;
typedef __attribute__((ext_vector_type(4))) float f32x4;

// round-half-up bf16 pack: 2x v_add + 1x v_perm
__device__ __forceinline__ unsigned int pack2(float lo, float hi) {
    unsigned int a = __float_as_uint(lo) + 0x8000u;
    unsigned int b = __float_as_uint(hi) + 0x8000u;
    return __builtin_amdgcn_perm(b, a, 0x07060302u);
}
__device__ __forceinline__ float nneg(float x) {
    return x < 0.f ? __expf(x) : x + 1.f;
}
__device__ __forceinline__ short8 ld_frag(const unsigned int* p) {
    uint2 a = *(const uint2*)p;
    uint2 b = *(const uint2*)(p + 2);
    union { unsigned int u[4]; short8 s; } r;
    r.u[0] = a.x; r.u[1] = a.y; r.u[2] = b.x; r.u[3] = b.y;
    return r.s;
}

// ---------------------------------------------------------------------------
// init: zero 4 MiB KV accumulator + detect token_mask storage (int32 vs byte)
// ---------------------------------------------------------------------------
__global__ __launch_bounds__(256) void k_init(float4* kv4, int* flag,
                                              const unsigned char* mask_raw) {
    int i = blockIdx.x * 256 + threadIdx.x;
    kv4[i] = make_float4(0.f, 0.f, 0.f, 0.f);   // grid sized exactly
    if (blockIdx.x == 0) {
        __shared__ int s_any;
        if (threadIdx.x == 0) s_any = 0;
        __syncthreads();
        int any = 0;
        int base = threadIdx.x * 16;
        #pragma unroll
        for (int j = 0; j < 16; j++) {
            int idx = base + j;
            if ((idx & 3) && mask_raw[idx]) any = 1;
        }
        if (any) s_any = 1;
        __syncthreads();
        if (threadIdx.x == 0) *flag = s_any ? 0 : 1;
    }
}

// ---------------------------------------------------------------------------
// phase 1: KV[d][e] = sum_s kf(k[s,d])*cos(s)*v[s,e]  (and sin variant)
// grid = 128 bh * 8 splits (512 s each), block=256, 8 chunks of 64 rows.
// DOUBLE-BUFFERED LDS, ONE barrier per chunk:
//   stage(buf c&1) -> barrier -> prefetch(c+1) -> MFMA(buf c&1)
// At the barrier the only outstanding vmem is last iteration's prefetch,
// already consumed by the transform -> vmcnt(0) drain is free.
// ---------------------------------------------------------------------------
__global__ __launch_bounds__(256) void k_phase1(const float* __restrict__ kk,
                                                const float* __restrict__ vv,
                                                float* __restrict__ kv) {
    __shared__ unsigned int lds[2 * 3 * LDSU];   // 52224 B
    const int t    = threadIdx.x;
    const int bh   = blockIdx.x >> 3;
    const int sblk = (blockIdx.x & 7) << 9;    // *512
    const int c    = t & 15;                   // d-group (4 d's)
    const int rp   = t >> 4;                   // s-quad 0..15
    const int lane = t & 63;
    const int w    = t >> 6;                   // wave id == e-tile
    const int n    = lane & 15;
    const int q4   = lane >> 4;
    const float* kb = kk + (size_t)bh * (Sn * Dn);
    const float* vb = vv + (size_t)bh * (Sn * Dn);

    f32x4 accC[4], accS[4];
    #pragma unroll
    for (int i = 0; i < 4; i++) {
        accC[i] = (f32x4){0.f, 0.f, 0.f, 0.f};
        accS[i] = (f32x4){0.f, 0.f, 0.f, 0.f};
    }

    float4 pk[2][4], pv[2][4];
    {   // preload chunk 0
        const float* kp = kb + (size_t)(sblk + rp * 4) * Dn + c * 4;
        const float* vp = vb + (size_t)(sblk + rp * 4) * Dn + c * 4;
        #pragma unroll
        for (int i = 0; i < 4; i++) {
            pk[0][i] = *(const float4*)(kp + i * Dn);
            pv[0][i] = *(const float4*)(vp + i * Dn);
        }
    }

    #pragma unroll
    for (int chunk = 0; chunk < 8; chunk++) {
        const int cur = chunk & 1, nxt = cur ^ 1;
        const int s0 = sblk + chunk * 64;
        unsigned int* bKc = lds + cur * (3 * LDSU);
        unsigned int* bKs = bKc + LDSU;
        unsigned int* bV  = bKs + LDSU;
        // ---- transform current chunk + stage to LDS (b64 writes) ----
        float cs[4], sn[4], fk[4][4], fv[4][4];
        #pragma unroll
        for (int i = 0; i < 4; i++) {
            __sincosf(CW * (float)(s0 + rp * 4 + i), &sn[i], &cs[i]);
            fk[i][0] = nneg(pk[cur][i].x); fk[i][1] = nneg(pk[cur][i].y);
            fk[i][2] = nneg(pk[cur][i].z); fk[i][3] = nneg(pk[cur][i].w);
            fv[i][0] = pv[cur][i].x; fv[i][1] = pv[cur][i].y;
            fv[i][2] = pv[cur][i].z; fv[i][3] = pv[cur][i].w;
        }
        #pragma unroll
        for (int j = 0; j < 4; j++) {
            int d = c * 4 + j;
            uint2 wc, wsn, wv;
            wc.x  = pack2(fk[0][j] * cs[0], fk[1][j] * cs[1]);
            wc.y  = pack2(fk[2][j] * cs[2], fk[3][j] * cs[3]);
            wsn.x = pack2(fk[0][j] * sn[0], fk[1][j] * sn[1]);
            wsn.y = pack2(fk[2][j] * sn[2], fk[3][j] * sn[3]);
            wv.x  = pack2(fv[0][j], fv[1][j]);
            wv.y  = pack2(fv[2][j], fv[3][j]);
            *(uint2*)&bKc[d * P1S + rp * 2] = wc;
            *(uint2*)&bKs[d * P1S + rp * 2] = wsn;
            *(uint2*)&bV [d * P1S + rp * 2] = wv;
        }
        __syncthreads();
        // ---- prefetch next chunk: full iteration to cover HBM latency ----
        if (chunk < 7) {
            const float* kp = kb + (size_t)(s0 + 64 + rp * 4) * Dn + c * 4;
            const float* vp = vb + (size_t)(s0 + 64 + rp * 4) * Dn + c * 4;
            #pragma unroll
            for (int i = 0; i < 4; i++) {
                pk[nxt][i] = *(const float4*)(kp + i * Dn);
                pv[nxt][i] = *(const float4*)(vp + i * Dn);
            }
        }
        // ---- MFMA: A = Kc^T/Ks^T (m=d,k=s), B = V (k=s,n=e) ----
        #pragma unroll
        for (int ks = 0; ks < 2; ks++) {
            short8 Bv = ld_frag(&bV[(w * 16 + n) * P1S + ks * 16 + q4 * 4]);
            #pragma unroll
            for (int dt = 0; dt < 4; dt++) {
                short8 Ac = ld_frag(&bKc[(dt * 16 + n) * P1S + ks * 16 + q4 * 4]);
                short8 As = ld_frag(&bKs[(dt * 16 + n) * P1S + ks * 16 + q4 * 4]);
                accC[dt] = __builtin_amdgcn_mfma_f32_16x16x32_bf16(Ac, Bv, accC[dt], 0, 0, 0);
                accS[dt] = __builtin_amdgcn_mfma_f32_16x16x32_bf16(As, Bv, accS[dt], 0, 0, 0);
            }
        }
        // no second barrier: next stage writes the OTHER buffer
    }
    // ---- atomics into KV[d][e]: 16 contiguous lanes per line ----
    float* base = kv + (size_t)bh * 2 * 4096;
    const int e = w * 16 + n;
    #pragma unroll
    for (int dt = 0; dt < 4; dt++) {
        #pragma unroll
        for (int r = 0; r < 4; r++) {
            int d = dt * 16 + q4 * 4 + r;   // C layout: row = quad*4 + reg
            atomicAdd(base +        d * 64 + e, accC[dt][r]);
            atomicAdd(base + 4096 + d * 64 + e, accS[dt][r]);
        }
    }
}

// ---------------------------------------------------------------------------
// phase 2: out[s,e] = (qc[s,:]·KV_c[:,e] + qs[s,:]·KV_s[:,e]) * 0.125
// grid = 128 bh * 16 chunks (256 s each), block=256, 4 strips of 64 s.
// B-frags gathered from global KV[d][e] (L2-hot), no LDS/barriers.
// ---------------------------------------------------------------------------
__global__ __launch_bounds__(256) void k_phase2(const float* __restrict__ qq,
                                                const void* __restrict__ mask_raw,
                                                const float* __restrict__ kv,
                                                const int* __restrict__ flag,
                                                float* __restrict__ out) {
    const int t    = threadIdx.x;
    const int bh   = blockIdx.x >> 4;
    const int sblk = (blockIdx.x & 15) << 8;
    const int b    = bh >> 4;                  // H = 16
    const int lane = t & 63;
    const int w    = t >> 6;
    const int n    = lane & 15;
    const int q4   = lane >> 4;
    const int iflag = *flag;

    // ---- gather B-frags from KV[d][e] (fp32 -> bf16) ----
    const float* kvb = kv + (size_t)bh * 8192;
    short8 Bc[4][2], Bs[4][2];
    #pragma unroll
    for (int et = 0; et < 4; et++) {
        const int e = et * 16 + n;
        #pragma unroll
        for (int ks = 0; ks < 2; ks++) {
            const int d0 = ks * 32 + q4 * 8;
            union { unsigned int u[4]; short8 s; } uc, us;
            #pragma unroll
            for (int jj = 0; jj < 4; jj++) {
                float c0 = kvb[(size_t)(d0 + 2 * jj)     * 64 + e];
                float c1 = kvb[(size_t)(d0 + 2 * jj + 1) * 64 + e];
                float s0 = kvb[4096 + (size_t)(d0 + 2 * jj)     * 64 + e];
                float s1 = kvb[4096 + (size_t)(d0 + 2 * jj + 1) * 64 + e];
                uc.u[jj] = pack2(c0, c1);
                us.u[jj] = pack2(s0, s1);
            }
            Bc[et][ks] = uc.s;
            Bs[et][ks] = us.s;
        }
    }

    const float* qb = qq + (size_t)bh * (Sn * Dn);
    float* ob       = out + (size_t)bh * (Sn * Dn);
    const unsigned char* m8 = (const unsigned char*)mask_raw;
    const int* m32          = (const int*)mask_raw;

    float4 pq[2][4];
    float  pmv[2];
    {   // preload strip 0
        int s_row = sblk + w * 16 + n;
        const float* qp = qb + (size_t)s_row * Dn + q4 * 8;
        pq[0][0] = *(const float4*)(qp);
        pq[0][1] = *(const float4*)(qp + 4);
        pq[0][2] = *(const float4*)(qp + 32);
        pq[0][3] = *(const float4*)(qp + 36);
        pmv[0] = iflag ? (m32[b * Sn + s_row] ? 1.f : 0.f)
                       : (m8 [b * Sn + s_row] ? 1.f : 0.f);
    }

    #pragma unroll
    for (int strip = 0; strip < 4; strip++) {
        const int cur = strip & 1, nxt = cur ^ 1;
        const int s_base = sblk + strip * 64 + w * 16;
        const int s_row  = s_base + n;         // A-layout: m = lane&15
        float cs, snv;
        __sincosf(CW * (float)s_row, &snv, &cs);
        cs *= pmv[cur]; snv *= pmv[cur];
        float f[16];
        f[0]  = nneg(pq[cur][0].x); f[1]  = nneg(pq[cur][0].y);
        f[2]  = nneg(pq[cur][0].z); f[3]  = nneg(pq[cur][0].w);
        f[4]  = nneg(pq[cur][1].x); f[5]  = nneg(pq[cur][1].y);
        f[6]  = nneg(pq[cur][1].z); f[7]  = nneg(pq[cur][1].w);
        f[8]  = nneg(pq[cur][2].x); f[9]  = nneg(pq[cur][2].y);
        f[10] = nneg(pq[cur][2].z); f[11] = nneg(pq[cur][2].w);
        f[12] = nneg(pq[cur][3].x); f[13] = nneg(pq[cur][3].y);
        f[14] = nneg(pq[cur][3].z); f[15] = nneg(pq[cur][3].w);
        union { unsigned int u[4]; short8 s; } ac0, as0, ac1, as1;
        #pragma unroll
        for (int j = 0; j < 4; j++) {
            ac0.u[j] = pack2(f[2*j]     * cs,  f[2*j + 1]     * cs);
            as0.u[j] = pack2(f[2*j]     * snv, f[2*j + 1]     * snv);
            ac1.u[j] = pack2(f[8 + 2*j] * cs,  f[8 + 2*j + 1] * cs);
            as1.u[j] = pack2(f[8 + 2*j] * snv, f[8 + 2*j + 1] * snv);
        }
        // ---- prefetch next strip's q + mask ----
        if (strip < 3) {
            int s_row2 = sblk + (strip + 1) * 64 + w * 16 + n;
            const float* qp = qb + (size_t)s_row2 * Dn + q4 * 8;
            pq[nxt][0] = *(const float4*)(qp);
            pq[nxt][1] = *(const float4*)(qp + 4);
            pq[nxt][2] = *(const float4*)(qp + 32);
            pq[nxt][3] = *(const float4*)(qp + 36);
            pmv[nxt] = iflag ? (m32[b * Sn + s_row2] ? 1.f : 0.f)
                             : (m8 [b * Sn + s_row2] ? 1.f : 0.f);
        }
        f32x4 acc[4];
        #pragma unroll
        for (int et = 0; et < 4; et++) acc[et] = (f32x4){0.f, 0.f, 0.f, 0.f};
        #pragma unroll
        for (int et = 0; et < 4; et++) {
            acc[et] = __builtin_amdgcn_mfma_f32_16x16x32_bf16(ac0.s, Bc[et][0], acc[et], 0, 0, 0);
            acc[et] = __builtin_amdgcn_mfma_f32_16x16x32_bf16(ac1.s, Bc[et][1], acc[et], 0, 0, 0);
            acc[et] = __builtin_amdgcn_mfma_f32_16x16x32_bf16(as0.s, Bs[et][0], acc[et], 0, 0, 0);
            acc[et] = __builtin_amdgcn_mfma_f32_16x16x32_bf16(as1.s, Bs[et][1], acc[et], 0, 0, 0);
        }
        // C layout: col = lane&15 (=e), row = quad*4 + reg (=s offset)
        #pragma unroll
        for (int et = 0; et < 4; et++) {
            #pragma unroll
            for (int r = 0; r < 4; r++) {
                int row = q4 * 4 + r;
                ob[(size_t)(s_base + row) * 64 + et * 16 + n] = acc[et][r] * 0.125f;
            }
        }
    }
}

extern "C" void kernel_launch(void* const* d_in, const int* in_sizes, int n_in,
                              void* d_out, int out_size, void* d_ws, size_t ws_size,
                              hipStream_t stream) {
    const float* q = (const float*)d_in[0];
    const float* k = (const float*)d_in[1];
    const float* v = (const float*)d_in[2];
    const void* mask = d_in[3];
    int*   flag = (int*)d_ws;
    float* kv   = (float*)((char*)d_ws + 256);   // 4 MiB KV accumulator

    k_init  <<<1024, 256, 0, stream>>>((float4*)kv, flag, (const unsigned char*)mask);
    k_phase1<<<1024, 256, 0, stream>>>(k, v, kv);
    k_phase2<<<2048, 256, 0, stream>>>(q, mask, kv, flag, (float*)d_out);
}